// Round 1
// baseline (16745.277 us; speedup 1.0000x reference)
//
#include <hip/hip_runtime.h>

// ============================================================================
// ESGP v4 — v3 + decoupled flag path:
//   * per-wave atomic counter flags (consumers poll count>=8) -> B2 removed,
//     flag completes at slowest wave's flush, not barrier+tid0.
//   * 2-deep pipelined flag polling (detect quantum RTT -> RTT/2, lower
//     variance); exits with ONE stale in-flight load absorbed by the vmcnt
//     ladder (WAITQ8F ties its regs so they can't be reallocated).
//   * prog1 published right after B1 (reads provably done), dout stores
//     moved off the flag path, s_part parity double-buffered (race closed
//     without B2).
// ============================================================================

#define T_STEPS 1024

typedef __attribute__((ext_vector_type(8))) short  bf16x8;
typedef __attribute__((ext_vector_type(4))) float  floatx4;

static __device__ __forceinline__ unsigned short f2bf(float f) {
  union { float f; unsigned u; } c; c.f = f;
  unsigned r = c.u + 0x7FFFu + ((c.u >> 16) & 1u);   // RNE
  return (unsigned short)(r >> 16);
}
static __device__ __forceinline__ float bf2f(unsigned short s) {
  union { unsigned u; float f; } c; c.u = ((unsigned)s) << 16; return c.f;
}

// LLC-coherent 16B load (bypass L1/L2; pairs with write-through ring stores)
static __device__ __forceinline__ void llc_load4(const void* p, floatx4& r) {
  asm volatile("global_load_dwordx4 %0, %1, off sc0 sc1" : "=v"(r) : "v"(p));
}
static __device__ __forceinline__ void llc_store_short(unsigned short* p, unsigned v) {
  asm volatile("global_store_short %0, %1, off sc0 sc1" :: "v"(p), "v"(v) : "memory");
}
static __device__ __forceinline__ void flush_vm() {
  asm volatile("s_waitcnt vmcnt(0)" ::: "memory");
}
#define WAITQ8(N, q) asm volatile("s_waitcnt vmcnt(" #N ")" \
  : "+v"((q)[0]), "+v"((q)[1]), "+v"((q)[2]), "+v"((q)[3]), \
    "+v"((q)[4]), "+v"((q)[5]), "+v"((q)[6]), "+v"((q)[7]) :: "memory")
// First wait of the ladder also ties the poll registers: guarantees the stale
// poll load (oldest outstanding) has completed before its regs are reused.
#define WAITQ8F(N, q, a, b) asm volatile("s_waitcnt vmcnt(" #N ")" \
  : "+v"((q)[0]), "+v"((q)[1]), "+v"((q)[2]), "+v"((q)[3]), \
    "+v"((q)[4]), "+v"((q)[5]), "+v"((q)[6]), "+v"((q)[7]), \
    "+v"(a), "+v"(b) :: "memory")

static __device__ __forceinline__ void poll_ge(const int* row, int lane, int target) {
  for (;;) {
    int v = __hip_atomic_load(row + lane, __ATOMIC_RELAXED, __HIP_MEMORY_SCOPE_AGENT);
    if (__all(v >= target)) break;
    __builtin_amdgcn_s_sleep(1);
  }
  asm volatile("" ::: "memory");
}

__global__ __launch_bounds__(512, 2) void esgp_v4(
    const float* __restrict__ x,
    const float* __restrict__ W_in0, const float* __restrict__ W_res0,
    const float* __restrict__ W_z0,  const float* __restrict__ U_z0,
    const float* __restrict__ b_z0,
    const float* __restrict__ W_in1, const float* __restrict__ W_res1,
    const float* __restrict__ W_z1,  const float* __restrict__ U_z1,
    const float* __restrict__ b_z1,
    float* __restrict__ dout,
    int* f0, int* f1, int* prog1,
    unsigned short* r0h, unsigned short* r0l,
    unsigned short* r1h, unsigned short* r1l)
{
  __shared__ float s_part[2][8][2][2][256];  // [parity][wave][z|t][bt][m*16+j] 64 KB
  __shared__ float s_hprev[512];             // fp32 h slice, lane-private (== tid)
  __shared__ float s_bias[16];

  const int tid  = threadIdx.x, lane = tid & 63, wid = tid >> 6;
  const int quad = lane >> 4, m = lane & 15;     // m: A-row-local / j-col-local
  const int layer = blockIdx.x >> 6, jb = blockIdx.x & 63;
  const int jbase = jb * 16, jrow = jbase + m;

  s_hprev[tid] = 0.f;
  if (tid < 16) s_bias[tid] = (layer ? b_z1 : b_z0)[jbase + tid];

  unsigned short* oH = layer ? r1h : r0h;
  unsigned short* oL = layer ? r1l : r0l;
  int* fRow = layer ? f1 : f0;

  // B-fragment loader: lane holds W[jrow][kofs + kt*32 + quad*8 + e], split hi/lo
  auto loadW = [&](const float* W, int Kfull, int kofs, int nkt,
                   bf16x8* whi, bf16x8* wlo) {
    const float* wr = W + (size_t)jrow * Kfull + kofs + quad * 8;
    for (int kt = 0; kt < nkt; ++kt) {
      floatx4 v0 = *(const floatx4*)(wr + kt * 32);
      floatx4 v1 = *(const floatx4*)(wr + kt * 32 + 4);
      bf16x8 h, l;
      #pragma unroll
      for (int e = 0; e < 8; ++e) {
        float f = (e < 4) ? v0[e] : v1[e - 4];
        unsigned short hb = f2bf(f);
        h[e] = (short)hb;
        l[e] = (short)f2bf(f - bf2f(hb));
      }
      whi[kt] = h; wlo[kt] = l;
    }
  };

  // gate + publish (every wave; lane owns (b = wid*4+quad, j = m)).
  // Per-wave tail: flush own stores, then one atomicAdd on the step counter.
  auto gate = [&](int t) {
    const int p = t & 1;
    const int b = wid * 4 + quad, bt = b >> 4;
    const int fi = (b & 15) * 16 + m;
    float zp = s_bias[m], tp2 = 0.f;
    #pragma unroll
    for (int w = 0; w < 8; ++w) {
      zp  += s_part[p][w][0][bt][fi];
      tp2 += s_part[p][w][1][bt][fi];
    }
    float sg = 1.f / (1.f + __expf(-zp));
    float th = 1.f - 2.f / (__expf(2.f * tp2) + 1.f);
    float hp = s_hprev[tid];
    float hn = hp + sg * (th - hp);
    s_hprev[tid] = hn;
    unsigned short hb = f2bf(hn);
    unsigned short lb = f2bf(hn - bf2f(hb));
    const int ri = (t & 7) * 32768 + b * 1024 + jbase + m;
    llc_store_short(oH + ri, (unsigned)hb);
    llc_store_short(oL + ri, (unsigned)lb);
    flush_vm();                              // ring stores at LLC before flag
    if (lane == 0)
      __hip_atomic_fetch_add(fRow + t * 64 + jb, 1,
                             __ATOMIC_RELAXED, __HIP_MEMORY_SCOPE_AGENT);
    // output stores off the flag path (drained by later ladders/next flush)
    if (layer) dout[((size_t)b * T_STEPS + t) * 1024 + jbase + m] = hn;
    if (t == T_STEPS - 1)
      dout[(size_t)33554432 + (size_t)layer * 32768 + (size_t)b * 1024 + jbase + m] = hn;
  };

  if (layer == 1 || wid < 4) {
    // ---- h-side wave: 256-wide K-slice of one ring source, both gate mats --
    const float* Wz; const float* Wt;
    const unsigned short* pAh; const unsigned short* pAl;
    const int* fArr; int tOff;
    if (layer == 0)      { Wz = U_z0; Wt = W_res0; pAh = r0h; pAl = r0l; fArr = f0; tOff = 1; }
    else if (wid < 4)    { Wz = W_z1; Wt = W_in1;  pAh = r0h; pAl = r0l; fArr = f0; tOff = 0; }
    else                 { Wz = U_z1; Wt = W_res1; pAh = r1h; pAl = r1l; fArr = f1; tOff = 1; }
    const int wsub = wid & 3, kslice = wsub * 256;

    bf16x8 wzh[8], wzl[8], wth[8], wtl[8];
    loadW(Wz, 1024, kslice, 8, wzh, wzl);
    loadW(Wt, 1024, kslice, 8, wth, wtl);
    __syncthreads();

    int pv0 = 8, pv1 = 8;                    // 2-deep poll pipeline regs

    // 2-deep pipelined counter poll; exits with EXACTLY one stale load in
    // flight (absorbed by the first vmcnt(8) of the data ladder).
    auto pollc = [&](const int* row) {
      const int* a = row + (lane & 15);
      asm volatile("global_load_dword %0, %1, off sc0 sc1" : "=v"(pv0) : "v"(a));
      for (;;) {
        asm volatile("global_load_dword %0, %1, off sc0 sc1" : "=v"(pv1) : "v"(a));
        asm volatile("s_waitcnt vmcnt(1)" : "+v"(pv0) :: "memory");
        if (__all(pv0 >= 8)) break;
        asm volatile("global_load_dword %0, %1, off sc0 sc1" : "=v"(pv0) : "v"(a));
        asm volatile("s_waitcnt vmcnt(1)" : "+v"(pv1) :: "memory");
        if (__all(pv1 >= 8)) break;
      }
    };

    for (int t = 0; t < T_STEPS; ++t) {
      // throttle first (fully drains), so pollc's stale survives to the ladder
      if (layer == 0 && t >= 8 && (t & 3) == 0) poll_ge(prog1, lane, t - 4);
      const int tp = t - tOff;
      if (tp >= 0) pollc(fArr + tp * 64 + wsub * 16);

      const int slot = tp & 7;
      const unsigned short* bh = pAh + slot * 32768;
      const unsigned short* bl = pAl + slot * 32768;

      floatx4 q0[8], q1[8];
      floatx4 accz[2] = {{0,0,0,0},{0,0,0,0}};
      floatx4 acct[2] = {{0,0,0,0},{0,0,0,0}};

      auto issueG = [&](int g, floatx4* Q) {
        const int kb = kslice + g * 64 + quad * 8;
        #pragma unroll
        for (int kt2 = 0; kt2 < 2; ++kt2)
          #pragma unroll
          for (int bt = 0; bt < 2; ++bt) {
            const int off = (bt * 16 + m) * 1024 + kb + kt2 * 32;
            llc_load4(bh + off, Q[(kt2 * 2 + bt) * 2 + 0]);
            llc_load4(bl + off, Q[(kt2 * 2 + bt) * 2 + 1]);
          }
      };
      auto mfmaG = [&](int g, floatx4* Q) {
        #pragma unroll
        for (int kt2 = 0; kt2 < 2; ++kt2) {
          const int kg = g * 2 + kt2;
          #pragma unroll
          for (int bt = 0; bt < 2; ++bt) {
            bf16x8 ah = *(bf16x8*)&Q[(kt2 * 2 + bt) * 2 + 0];
            bf16x8 al = *(bf16x8*)&Q[(kt2 * 2 + bt) * 2 + 1];
            accz[bt] = __builtin_amdgcn_mfma_f32_16x16x32_bf16(ah, wzh[kg], accz[bt], 0, 0, 0);
            accz[bt] = __builtin_amdgcn_mfma_f32_16x16x32_bf16(al, wzh[kg], accz[bt], 0, 0, 0);
            accz[bt] = __builtin_amdgcn_mfma_f32_16x16x32_bf16(ah, wzl[kg], accz[bt], 0, 0, 0);
            acct[bt] = __builtin_amdgcn_mfma_f32_16x16x32_bf16(ah, wth[kg], acct[bt], 0, 0, 0);
            acct[bt] = __builtin_amdgcn_mfma_f32_16x16x32_bf16(al, wth[kg], acct[bt], 0, 0, 0);
            acct[bt] = __builtin_amdgcn_mfma_f32_16x16x32_bf16(ah, wtl[kg], acct[bt], 0, 0, 0);
          }
        }
      };

      issueG(0, q0); issueG(1, q1);
      WAITQ8F(8, q0, pv0, pv1);              // drains stale poll + older acks + q0
      mfmaG(0, q0); issueG(2, q0);
      WAITQ8(8, q1); mfmaG(1, q1); issueG(3, q1);
      WAITQ8(8, q0); mfmaG(2, q0);
      WAITQ8(0, q1); mfmaG(3, q1);

      #pragma unroll
      for (int r = 0; r < 4; ++r) {
        #pragma unroll
        for (int bt = 0; bt < 2; ++bt) {
          s_part[t & 1][wid][0][bt][(quad * 4 + r) * 16 + m] = accz[bt][r];
          s_part[t & 1][wid][1][bt][(quad * 4 + r) * 16 + m] = acct[bt][r];
        }
      }
      __syncthreads();                       // B1 (only barrier per step)
      if (layer && tid == 0)                 // reads of r0/r1 slot provably done
        __hip_atomic_store(prog1 + jb, t + 1, __ATOMIC_RELAXED, __HIP_MEMORY_SCOPE_AGENT);
      gate(t);
    }
  } else {
    // ---- x-side wave (layer 0, wid 4..7): 128-wide K-slice of x ------------
    const int wsub2 = wid - 4, kofs = wsub2 * 128;
    bf16x8 wzh[4], wzl[4], wth[4], wtl[4];
    loadW(W_z0,  512, kofs, 4, wzh, wzl);
    loadW(W_in0, 512, kofs, 4, wth, wtl);
    __syncthreads();

    for (int t = 0; t < T_STEPS; ++t) {
      if (t >= 8 && (t & 3) == 0) poll_ge(prog1, lane, t - 4);

      floatx4 xa[16];
      const float* xb = x + (size_t)t * 512 + kofs + quad * 8;
      #pragma unroll
      for (int kt = 0; kt < 4; ++kt)
        #pragma unroll
        for (int bt = 0; bt < 2; ++bt) {
          const float* p = xb + (size_t)(bt * 16 + m) * 524288 + kt * 32;
          xa[(kt * 2 + bt) * 2 + 0] = *(const floatx4*)p;
          xa[(kt * 2 + bt) * 2 + 1] = *(const floatx4*)(p + 4);
        }

      floatx4 accz[2] = {{0,0,0,0},{0,0,0,0}};
      floatx4 acct[2] = {{0,0,0,0},{0,0,0,0}};
      #pragma unroll
      for (int kt = 0; kt < 4; ++kt)
        #pragma unroll
        for (int bt = 0; bt < 2; ++bt) {
          floatx4 v0 = xa[(kt * 2 + bt) * 2 + 0];
          floatx4 v1 = xa[(kt * 2 + bt) * 2 + 1];
          bf16x8 ah, al;
          #pragma unroll
          for (int e = 0; e < 8; ++e) {
            float f = (e < 4) ? v0[e] : v1[e - 4];
            unsigned short hb = f2bf(f);
            ah[e] = (short)hb;
            al[e] = (short)f2bf(f - bf2f(hb));
          }
          accz[bt] = __builtin_amdgcn_mfma_f32_16x16x32_bf16(ah, wzh[kt], accz[bt], 0, 0, 0);
          accz[bt] = __builtin_amdgcn_mfma_f32_16x16x32_bf16(al, wzh[kt], accz[bt], 0, 0, 0);
          accz[bt] = __builtin_amdgcn_mfma_f32_16x16x32_bf16(ah, wzl[kt], accz[bt], 0, 0, 0);
          acct[bt] = __builtin_amdgcn_mfma_f32_16x16x32_bf16(ah, wth[kt], acct[bt], 0, 0, 0);
          acct[bt] = __builtin_amdgcn_mfma_f32_16x16x32_bf16(al, wth[kt], acct[bt], 0, 0, 0);
          acct[bt] = __builtin_amdgcn_mfma_f32_16x16x32_bf16(ah, wtl[kt], acct[bt], 0, 0, 0);
        }

      #pragma unroll
      for (int r = 0; r < 4; ++r) {
        #pragma unroll
        for (int bt = 0; bt < 2; ++bt) {
          s_part[t & 1][wid][0][bt][(quad * 4 + r) * 16 + m] = accz[bt][r];
          s_part[t & 1][wid][1][bt][(quad * 4 + r) * 16 + m] = acct[bt][r];
        }
      }
      __syncthreads();                       // B1
      gate(t);
    }
  }
}

// ---------------------------------------------------------------------------
// Workspace layout (bytes):
//   f0:    0x000000  1024*64 ints (per-step counters, 8 adds each)
//   f1:    0x040000   prog1: 0x080000
//   r0h:   0x100000  8 slots * 32*1024 bf16 (512 KB)   r0l: 0x180000
//   r1h:   0x200000                                     r1l: 0x280000
//   total: 0x300000 = 3 MiB (memset 0: counters clear, rings = h(-1) = 0)
// ---------------------------------------------------------------------------
extern "C" void kernel_launch(void* const* d_in, const int* in_sizes, int n_in,
                              void* d_out, int out_size, void* d_ws, size_t ws_size,
                              hipStream_t stream) {
  const float* x      = (const float*)d_in[0];
  const float* W_in0  = (const float*)d_in[2];
  const float* W_res0 = (const float*)d_in[3];
  const float* W_z0   = (const float*)d_in[4];
  const float* U_z0   = (const float*)d_in[5];
  const float* b_z0   = (const float*)d_in[6];
  const float* W_in1  = (const float*)d_in[7];
  const float* W_res1 = (const float*)d_in[8];
  const float* W_z1   = (const float*)d_in[9];
  const float* U_z1   = (const float*)d_in[10];
  const float* b_z1   = (const float*)d_in[11];
  float* out = (float*)d_out;

  char* ws = (char*)d_ws;
  int*   f0    = (int*)(ws + 0x000000);
  int*   f1    = (int*)(ws + 0x040000);
  int*   prog1 = (int*)(ws + 0x080000);
  unsigned short* r0h = (unsigned short*)(ws + 0x100000);
  unsigned short* r0l = (unsigned short*)(ws + 0x180000);
  unsigned short* r1h = (unsigned short*)(ws + 0x200000);
  unsigned short* r1l = (unsigned short*)(ws + 0x280000);

  hipMemsetAsync(d_ws, 0, 0x300000, stream);

  esgp_v4<<<dim3(128), dim3(512), 0, stream>>>(
      x, W_in0, W_res0, W_z0, U_z0, b_z0,
      W_in1, W_res1, W_z1, U_z1, b_z1,
      out, f0, f1, prog1, r0h, r0l, r1h, r1l);
}

// Round 2
// 13442.349 us; speedup vs baseline: 1.2457x; 1.2457x over previous
//
#include <hip/hip_runtime.h>

// ============================================================================
// ESGP v5 — v3 skeleton + flag-free "tagged data" protocol:
//   * Every ring short carries a generation-parity tag in its LSB
//     (tag = ((t>>3)&1)^1; inverted so gen 0..7 != memset zeros).
//     lo-plane is computed AFTER tagging hi, so hi's LSB error is absorbed;
//     net perturbation ~2^-16 relative.
//   * Consumers validate tags on the loaded data registers (cheap VALU) and
//     retry the group only if stale -> NO flag arrays, NO producer flush,
//     NO second barrier, NO separate flag-detect RTT. 2-3 serial IC
//     transactions removed per step.
//   * s_part parity double-buffered (closes the race B2 used to close).
//   * Slot reuse guarded exactly as v3: prog1 throttle (L0 waits L1 >= t-4)
//     + <=1-step intra-layer skew (every block validates every producer).
//     Tag parity flips every 8 generations -> stale reads spin, never corrupt.
// ============================================================================

#define T_STEPS 1024

typedef __attribute__((ext_vector_type(8))) short  bf16x8;
typedef __attribute__((ext_vector_type(4))) float  floatx4;
typedef __attribute__((ext_vector_type(4))) int    intx4;

static __device__ __forceinline__ unsigned short f2bf(float f) {
  union { float f; unsigned u; } c; c.f = f;
  unsigned r = c.u + 0x7FFFu + ((c.u >> 16) & 1u);   // RNE
  return (unsigned short)(r >> 16);
}
static __device__ __forceinline__ float bf2f(unsigned short s) {
  union { unsigned u; float f; } c; c.u = ((unsigned)s) << 16; return c.f;
}

// LLC-coherent 16B load (bypass L1/L2; pairs with write-through ring stores)
static __device__ __forceinline__ void llc_load4(const void* p, floatx4& r) {
  asm volatile("global_load_dwordx4 %0, %1, off sc0 sc1" : "=v"(r) : "v"(p));
}
static __device__ __forceinline__ void llc_store_short(unsigned short* p, unsigned v) {
  asm volatile("global_store_short %0, %1, off sc0 sc1" :: "v"(p), "v"(v) : "memory");
}
#define WAITQ8(N, q) asm volatile("s_waitcnt vmcnt(" #N ")" \
  : "+v"((q)[0]), "+v"((q)[1]), "+v"((q)[2]), "+v"((q)[3]), \
    "+v"((q)[4]), "+v"((q)[5]), "+v"((q)[6]), "+v"((q)[7]) :: "memory")

static __device__ __forceinline__ void poll_ge(const int* row, int lane, int target) {
  for (;;) {
    int v = __hip_atomic_load(row + lane, __ATOMIC_RELAXED, __HIP_MEMORY_SCOPE_AGENT);
    if (__all(v >= target)) break;
    __builtin_amdgcn_s_sleep(1);
  }
  asm volatile("" ::: "memory");
}

__global__ __launch_bounds__(512, 2) void esgp_v5(
    const float* __restrict__ x,
    const float* __restrict__ W_in0, const float* __restrict__ W_res0,
    const float* __restrict__ W_z0,  const float* __restrict__ U_z0,
    const float* __restrict__ b_z0,
    const float* __restrict__ W_in1, const float* __restrict__ W_res1,
    const float* __restrict__ W_z1,  const float* __restrict__ U_z1,
    const float* __restrict__ b_z1,
    float* __restrict__ dout,
    int* prog1,
    unsigned short* r0h, unsigned short* r0l,
    unsigned short* r1h, unsigned short* r1l)
{
  __shared__ float s_part[2][8][2][2][256];  // [parity][wave][z|t][bt][m*16+j] 64 KB
  __shared__ float s_hprev[512];             // fp32 h slice, lane-private (== tid)
  __shared__ float s_bias[16];

  const int tid  = threadIdx.x, lane = tid & 63, wid = tid >> 6;
  const int quad = lane >> 4, m = lane & 15;     // m: A-row-local / j-col-local
  const int layer = blockIdx.x >> 6, jb = blockIdx.x & 63;
  const int jbase = jb * 16, jrow = jbase + m;

  s_hprev[tid] = 0.f;
  if (tid < 16) s_bias[tid] = (layer ? b_z1 : b_z0)[jbase + tid];

  unsigned short* oH = layer ? r1h : r0h;
  unsigned short* oL = layer ? r1l : r0l;

  // B-fragment loader: lane holds W[jrow][kofs + kt*32 + quad*8 + e], split hi/lo
  auto loadW = [&](const float* W, int Kfull, int kofs, int nkt,
                   bf16x8* whi, bf16x8* wlo) {
    const float* wr = W + (size_t)jrow * Kfull + kofs + quad * 8;
    for (int kt = 0; kt < nkt; ++kt) {
      floatx4 v0 = *(const floatx4*)(wr + kt * 32);
      floatx4 v1 = *(const floatx4*)(wr + kt * 32 + 4);
      bf16x8 h, l;
      #pragma unroll
      for (int e = 0; e < 8; ++e) {
        float f = (e < 4) ? v0[e] : v1[e - 4];
        unsigned short hb = f2bf(f);
        h[e] = (short)hb;
        l[e] = (short)f2bf(f - bf2f(hb));
      }
      whi[kt] = h; wlo[kt] = l;
    }
  };

  // gate + tagged publish (every wave; lane owns (b = wid*4+quad, j = m)).
  // No flush, no barrier, no flag: the tag bits ARE the flag.
  auto gate = [&](int t) {
    const int p = t & 1;
    const int b = wid * 4 + quad, bt = b >> 4;
    const int fi = (b & 15) * 16 + m;
    float zp = s_bias[m], tp2 = 0.f;
    #pragma unroll
    for (int w = 0; w < 8; ++w) {
      zp  += s_part[p][w][0][bt][fi];
      tp2 += s_part[p][w][1][bt][fi];
    }
    float sg = 1.f / (1.f + __expf(-zp));
    float th = 1.f - 2.f / (__expf(2.f * tp2) + 1.f);
    float hp = s_hprev[tid];
    float hn = hp + sg * (th - hp);
    s_hprev[tid] = hn;
    const unsigned tagbit = ((unsigned)((t >> 3) & 1)) ^ 1u;
    unsigned hb = f2bf(hn);
    hb = (hb & 0xFFFEu) | tagbit;                     // tag hi; lo absorbs error
    unsigned lb = f2bf(hn - bf2f((unsigned short)hb));
    lb = (lb & 0xFFFEu) | tagbit;                     // tag lo (~2^-16 noise)
    const int ri = (t & 7) * 32768 + b * 1024 + jbase + m;
    llc_store_short(oH + ri, hb);
    llc_store_short(oL + ri, lb);
    if (layer) dout[((size_t)b * T_STEPS + t) * 1024 + jbase + m] = hn;
    if (t == T_STEPS - 1)
      dout[(size_t)33554432 + (size_t)layer * 32768 + (size_t)b * 1024 + jbase + m] = hn;
  };

  if (layer == 1 || wid < 4) {
    // ---- h-side wave: 256-wide K-slice of one ring source, both gate mats --
    const float* Wz; const float* Wt;
    const unsigned short* pAh; const unsigned short* pAl;
    int tOff;
    if (layer == 0)      { Wz = U_z0; Wt = W_res0; pAh = r0h; pAl = r0l; tOff = 1; }
    else if (wid < 4)    { Wz = W_z1; Wt = W_in1;  pAh = r0h; pAl = r0l; tOff = 0; }
    else                 { Wz = U_z1; Wt = W_res1; pAh = r1h; pAl = r1l; tOff = 1; }
    const int wsub = wid & 3, kslice = wsub * 256;

    bf16x8 wzh[8], wzl[8], wth[8], wtl[8];
    loadW(Wz, 1024, kslice, 8, wzh, wzl);
    loadW(Wt, 1024, kslice, 8, wth, wtl);
    __syncthreads();

    for (int t = 0; t < T_STEPS; ++t) {
      if (layer == 0 && t >= 8 && (t & 3) == 0) poll_ge(prog1, lane, t - 4);
      const int tp = t - tOff;
      const int slot = tp & 7;
      const unsigned short* bh = pAh + slot * 32768;
      const unsigned short* bl = pAl + slot * 32768;
      // expected tag word for generation tp (2 shorts per dword)
      const unsigned want = (tp >= 0 && ((((tp >> 3) & 1) ^ 1) != 0)) ? 0x00010001u : 0u;
      const bool doVal = (tp >= 0);

      floatx4 q0[8], q1[8];
      floatx4 accz[2] = {{0,0,0,0},{0,0,0,0}};
      floatx4 acct[2] = {{0,0,0,0},{0,0,0,0}};

      auto issueG = [&](int g, floatx4* Q) {
        const int kb = kslice + g * 64 + quad * 8;
        #pragma unroll
        for (int kt2 = 0; kt2 < 2; ++kt2)
          #pragma unroll
          for (int bt = 0; bt < 2; ++bt) {
            const int off = (bt * 16 + m) * 1024 + kb + kt2 * 32;
            llc_load4(bh + off, Q[(kt2 * 2 + bt) * 2 + 0]);
            llc_load4(bl + off, Q[(kt2 * 2 + bt) * 2 + 1]);
          }
      };
      // validate tags of a group's 8 chunks; retry (reissue + drain) if stale.
      auto valRetry = [&](int g, floatx4* Q) {
        if (!doVal) return;
        for (;;) {
          unsigned bad = 0;
          #pragma unroll
          for (int i = 0; i < 8; ++i) {
            const intx4 w = *(const intx4*)&Q[i];
            bad |= (unsigned)((w[0] ^ (int)want) | (w[1] ^ (int)want) |
                              (w[2] ^ (int)want) | (w[3] ^ (int)want));
          }
          if (__all((bad & 0x00010001u) == 0u)) break;
          __builtin_amdgcn_s_sleep(1);
          issueG(g, Q);                    // slow path: reload whole group
          WAITQ8(0, Q);                    // drain (other groups land too - ok)
        }
      };
      auto mfmaG = [&](int g, floatx4* Q) {
        #pragma unroll
        for (int kt2 = 0; kt2 < 2; ++kt2) {
          const int kg = g * 2 + kt2;
          #pragma unroll
          for (int bt = 0; bt < 2; ++bt) {
            bf16x8 ah = *(bf16x8*)&Q[(kt2 * 2 + bt) * 2 + 0];
            bf16x8 al = *(bf16x8*)&Q[(kt2 * 2 + bt) * 2 + 1];
            accz[bt] = __builtin_amdgcn_mfma_f32_16x16x32_bf16(ah, wzh[kg], accz[bt], 0, 0, 0);
            accz[bt] = __builtin_amdgcn_mfma_f32_16x16x32_bf16(al, wzh[kg], accz[bt], 0, 0, 0);
            accz[bt] = __builtin_amdgcn_mfma_f32_16x16x32_bf16(ah, wzl[kg], accz[bt], 0, 0, 0);
            acct[bt] = __builtin_amdgcn_mfma_f32_16x16x32_bf16(ah, wth[kg], acct[bt], 0, 0, 0);
            acct[bt] = __builtin_amdgcn_mfma_f32_16x16x32_bf16(al, wth[kg], acct[bt], 0, 0, 0);
            acct[bt] = __builtin_amdgcn_mfma_f32_16x16x32_bf16(ah, wtl[kg], acct[bt], 0, 0, 0);
          }
        }
      };

      issueG(0, q0); issueG(1, q1);
      WAITQ8(8, q0); valRetry(0, q0); mfmaG(0, q0); issueG(2, q0);
      WAITQ8(8, q1); valRetry(1, q1); mfmaG(1, q1); issueG(3, q1);
      WAITQ8(8, q0); valRetry(2, q0); mfmaG(2, q0);
      WAITQ8(0, q1); valRetry(3, q1); mfmaG(3, q1);

      #pragma unroll
      for (int r = 0; r < 4; ++r) {
        #pragma unroll
        for (int bt = 0; bt < 2; ++bt) {
          s_part[t & 1][wid][0][bt][(quad * 4 + r) * 16 + m] = accz[bt][r];
          s_part[t & 1][wid][1][bt][(quad * 4 + r) * 16 + m] = acct[bt][r];
        }
      }
      __syncthreads();                       // B1 (only barrier per step)
      if (layer && tid == 0)                 // r0/r1 slot reads provably done
        __hip_atomic_store(prog1 + jb, t + 1, __ATOMIC_RELAXED, __HIP_MEMORY_SCOPE_AGENT);
      gate(t);
    }
  } else {
    // ---- x-side wave (layer 0, wid 4..7): 128-wide K-slice of x ------------
    const int wsub2 = wid - 4, kofs = wsub2 * 128;
    bf16x8 wzh[4], wzl[4], wth[4], wtl[4];
    loadW(W_z0,  512, kofs, 4, wzh, wzl);
    loadW(W_in0, 512, kofs, 4, wth, wtl);
    __syncthreads();

    for (int t = 0; t < T_STEPS; ++t) {
      if (t >= 8 && (t & 3) == 0) poll_ge(prog1, lane, t - 4);

      floatx4 xa[16];
      const float* xb = x + (size_t)t * 512 + kofs + quad * 8;
      #pragma unroll
      for (int kt = 0; kt < 4; ++kt)
        #pragma unroll
        for (int bt = 0; bt < 2; ++bt) {
          const float* p = xb + (size_t)(bt * 16 + m) * 524288 + kt * 32;
          xa[(kt * 2 + bt) * 2 + 0] = *(const floatx4*)p;
          xa[(kt * 2 + bt) * 2 + 1] = *(const floatx4*)(p + 4);
        }

      floatx4 accz[2] = {{0,0,0,0},{0,0,0,0}};
      floatx4 acct[2] = {{0,0,0,0},{0,0,0,0}};
      #pragma unroll
      for (int kt = 0; kt < 4; ++kt)
        #pragma unroll
        for (int bt = 0; bt < 2; ++bt) {
          floatx4 v0 = xa[(kt * 2 + bt) * 2 + 0];
          floatx4 v1 = xa[(kt * 2 + bt) * 2 + 1];
          bf16x8 ah, al;
          #pragma unroll
          for (int e = 0; e < 8; ++e) {
            float f = (e < 4) ? v0[e] : v1[e - 4];
            unsigned short hb = f2bf(f);
            ah[e] = (short)hb;
            al[e] = (short)f2bf(f - bf2f(hb));
          }
          accz[bt] = __builtin_amdgcn_mfma_f32_16x16x32_bf16(ah, wzh[kt], accz[bt], 0, 0, 0);
          accz[bt] = __builtin_amdgcn_mfma_f32_16x16x32_bf16(al, wzh[kt], accz[bt], 0, 0, 0);
          accz[bt] = __builtin_amdgcn_mfma_f32_16x16x32_bf16(ah, wzl[kt], accz[bt], 0, 0, 0);
          acct[bt] = __builtin_amdgcn_mfma_f32_16x16x32_bf16(ah, wth[kt], acct[bt], 0, 0, 0);
          acct[bt] = __builtin_amdgcn_mfma_f32_16x16x32_bf16(al, wth[kt], acct[bt], 0, 0, 0);
          acct[bt] = __builtin_amdgcn_mfma_f32_16x16x32_bf16(ah, wtl[kt], acct[bt], 0, 0, 0);
        }

      #pragma unroll
      for (int r = 0; r < 4; ++r) {
        #pragma unroll
        for (int bt = 0; bt < 2; ++bt) {
          s_part[t & 1][wid][0][bt][(quad * 4 + r) * 16 + m] = accz[bt][r];
          s_part[t & 1][wid][1][bt][(quad * 4 + r) * 16 + m] = acct[bt][r];
        }
      }
      __syncthreads();                       // B1
      gate(t);
    }
  }
}

// ---------------------------------------------------------------------------
// Workspace layout (bytes):
//   prog1: 0x080000  (64 ints)
//   r0h:   0x100000  8 slots * 32*1024 bf16 (512 KB)   r0l: 0x180000
//   r1h:   0x200000                                     r1l: 0x280000
//   total: 0x300000 = 3 MiB (memset 0: prog1 clear, rings = h(-1) = 0 with
//   tag bits 0 -> distinct from generation-0 tag 1)
// ---------------------------------------------------------------------------
extern "C" void kernel_launch(void* const* d_in, const int* in_sizes, int n_in,
                              void* d_out, int out_size, void* d_ws, size_t ws_size,
                              hipStream_t stream) {
  const float* x      = (const float*)d_in[0];
  const float* W_in0  = (const float*)d_in[2];
  const float* W_res0 = (const float*)d_in[3];
  const float* W_z0   = (const float*)d_in[4];
  const float* U_z0   = (const float*)d_in[5];
  const float* b_z0   = (const float*)d_in[6];
  const float* W_in1  = (const float*)d_in[7];
  const float* W_res1 = (const float*)d_in[8];
  const float* W_z1   = (const float*)d_in[9];
  const float* U_z1   = (const float*)d_in[10];
  const float* b_z1   = (const float*)d_in[11];
  float* out = (float*)d_out;

  char* ws = (char*)d_ws;
  int*   prog1 = (int*)(ws + 0x080000);
  unsigned short* r0h = (unsigned short*)(ws + 0x100000);
  unsigned short* r0l = (unsigned short*)(ws + 0x180000);
  unsigned short* r1h = (unsigned short*)(ws + 0x200000);
  unsigned short* r1l = (unsigned short*)(ws + 0x280000);

  hipMemsetAsync(d_ws, 0, 0x300000, stream);

  esgp_v5<<<dim3(128), dim3(512), 0, stream>>>(
      x, W_in0, W_res0, W_z0, U_z0, b_z0,
      W_in1, W_res1, W_z1, U_z1, b_z1,
      out, prog1, r0h, r0l, r1h, r1l);
}